// Round 2
// baseline (444.719 us; speedup 1.0000x reference)
//
#include <hip/hip_runtime.h>
#include <stdint.h>

// Problem constants
// B=2, S=2048, D_IN=2048, H=16, G=4, D=128
// M = B*S = 4096 tokens; QKV N = H*D + 2*G*D = 2048+512+512 = 3072

typedef __attribute__((ext_vector_type(8))) short short8;   // 8 bf16 = 4 VGPRs
typedef __attribute__((ext_vector_type(4))) float f32x4;

__device__ __forceinline__ unsigned short f2bf(float f) {
  unsigned int u = __builtin_bit_cast(unsigned int, f);
  u += 0x7fffu + ((u >> 16) & 1u);   // RNE
  return (unsigned short)(u >> 16);
}

__device__ __forceinline__ void gl_lds16(const void* g, void* l) {
  __builtin_amdgcn_global_load_lds(
      (const __attribute__((address_space(1))) unsigned int*)g,
      (__attribute__((address_space(3))) unsigned int*)l, 16, 0, 0);
}

// ---------------------------------------------------------------------------
// Cast x (f32, row-major [4096][2048]) -> bf16 with per-row XOR swizzle:
// xb[m][k'] where k' = k ^ ((m&7)<<3)   (swizzle on 8-elem chunks)
// ---------------------------------------------------------------------------
__global__ __launch_bounds__(256) void k_cast_x(const float* __restrict__ x,
                                                unsigned short* __restrict__ xb) {
  int t = blockIdx.x * 256 + threadIdx.x;     // 1M threads, 8 elems each
  int m = t >> 8;
  int c = t & 255;                            // chunk of 8 within row
  const float* src = x + ((size_t)m * 2048 + (size_t)c * 8);
  float4 a = *(const float4*)src;
  float4 b = *(const float4*)(src + 4);
  uint4 o;
  o.x = f2bf(a.x) | ((unsigned)f2bf(a.y) << 16);
  o.y = f2bf(a.z) | ((unsigned)f2bf(a.w) << 16);
  o.z = f2bf(b.x) | ((unsigned)f2bf(b.y) << 16);
  o.w = f2bf(b.z) | ((unsigned)f2bf(b.w) << 16);
  *(uint4*)(xb + (size_t)m * 2048 + (size_t)((c ^ (m & 7)) * 8)) = o;
}

// ---------------------------------------------------------------------------
// Weight transpose+cast: W [K][N] f32  ->  WT [N][K] bf16 with row swizzle
// WT[n][k ^ ((n&7)<<3)] = W[k][n].  Tiles 64x64 via padded LDS.
// ---------------------------------------------------------------------------
__global__ __launch_bounds__(256) void k_wtrans(const float* __restrict__ W,
                                                unsigned short* __restrict__ WT,
                                                int K, int N) {
  __shared__ float tile[64][65];
  int k0 = blockIdx.x * 64, n0 = blockIdx.y * 64;
  int c = threadIdx.x & 63, r0 = threadIdx.x >> 6;
#pragma unroll
  for (int i = 0; i < 16; i++) {
    int kl = r0 + i * 4;
    tile[kl][c] = W[(size_t)(k0 + kl) * N + n0 + c];
  }
  __syncthreads();
#pragma unroll
  for (int i = 0; i < 16; i++) {
    int nl = r0 + i * 4;
    int n = n0 + nl;
    int sw = (n & 7) << 3;
    WT[(size_t)n * K + (size_t)((k0 + c) ^ sw)] = f2bf(tile[c][nl]);
  }
}

// ---------------------------------------------------------------------------
// V path: qkv f32 [4096][3072] (cols 2560..3071 = V) -> vts bf16 [(b*G+g)][d][s]
// with s swizzled within rows:  vts[bg][d][s ^ ((d&7)<<3)]
// ---------------------------------------------------------------------------
__global__ __launch_bounds__(256) void k_vtrans(const float* __restrict__ qkv,
                                                unsigned short* __restrict__ vts) {
  __shared__ float tile[64][65];
  int bg = blockIdx.z;
  int s0 = blockIdx.x * 64, d0 = blockIdx.y * 64;
  int b = bg >> 2, g = bg & 3;
  int c = threadIdx.x & 63, r0 = threadIdx.x >> 6;
#pragma unroll
  for (int i = 0; i < 16; i++) {
    int sl = r0 + i * 4;
    tile[sl][c] = qkv[(size_t)(b * 2048 + s0 + sl) * 3072 + 2560 + g * 128 + d0 + c];
  }
  __syncthreads();
#pragma unroll
  for (int i = 0; i < 16; i++) {
    int dl = r0 + i * 4;
    int d = d0 + dl;
    int sw = (d & 7) << 3;
    vts[((size_t)(bg * 128 + d)) * 2048 + (size_t)((s0 + c) ^ sw)] = f2bf(tile[c][dl]);
  }
}

// ---------------------------------------------------------------------------
// RMSNorm + RoPE.  One wave per (token, slot): slots 0..15 = q heads,
// 16..19 = k groups.  Lane holds d=lane and d=lane+64 (rotate-half is local).
// q gets * D^-0.5.  k written pre-swizzled for attention loads.
// ---------------------------------------------------------------------------
__global__ __launch_bounds__(256) void k_norm_rope(const float* __restrict__ qkv,
                                                   const float* __restrict__ cosT,
                                                   const float* __restrict__ sinT,
                                                   const float* __restrict__ qw,
                                                   const float* __restrict__ kw,
                                                   unsigned short* __restrict__ qh,
                                                   unsigned short* __restrict__ khs) {
  int wid = blockIdx.x * 4 + (threadIdx.x >> 6);
  int lane = threadIdx.x & 63;
  int slot = wid % 20;
  int token = wid / 20;              // 0..4095
  int b = token >> 11, s = token & 2047;
  int colbase = (slot < 16) ? slot * 128 : 2048 + (slot - 16) * 128;
  const float* base = qkv + (size_t)token * 3072 + colbase;
  float x1 = base[lane], x2 = base[lane + 64];
  float ss = x1 * x1 + x2 * x2;
#pragma unroll
  for (int o = 1; o < 64; o <<= 1) ss += __shfl_xor(ss, o);
  float rr = rsqrtf(ss * (1.0f / 128.0f) + 1e-6f);
  const float* wv = (slot < 16) ? qw : kw;
  float y1 = x1 * rr * wv[lane];
  float y2 = x2 * rr * wv[lane + 64];
  float c1 = cosT[s * 128 + lane], s1 = sinT[s * 128 + lane];
  float c2 = cosT[s * 128 + lane + 64], s2 = sinT[s * 128 + lane + 64];
  float o1 = y1 * c1 - y2 * s1;      // d < 64:  x*cos - x[d+64]*sin
  float o2 = y2 * c2 + y1 * s2;      // d >= 64: x*cos + x[d-64]*sin
  if (slot < 16) {
    const float sc = 0.08838834764831845f;   // 128^-0.5 folded into q
    unsigned short* dst = qh + ((size_t)((b * 16 + slot) * 2048 + s)) * 128;
    dst[lane] = f2bf(o1 * sc);
    dst[lane + 64] = f2bf(o2 * sc);
  } else {
    int g = slot - 16;
    unsigned short* dst = khs + ((size_t)((b * 4 + g) * 2048 + s)) * 128;
    int sw = (s & 7) << 3;
    dst[lane ^ sw] = f2bf(o1);
    dst[(lane + 64) ^ sw] = f2bf(o2);
  }
}

// ---------------------------------------------------------------------------
// GEMM C[M][N] f32 = A[M][K] * Bt[N][K]   (both bf16, rows XOR-swizzled)
// 128x128 tile, BK=64, 4 waves (64x64 quadrant each), double-buffered LDS,
// global_load_lds width-16, stage-next-before-compute, XCD swizzle.
// ---------------------------------------------------------------------------
__global__ __launch_bounds__(256, 2) void k_gemm(const unsigned short* __restrict__ A,
                                                 const unsigned short* __restrict__ Bt,
                                                 float* __restrict__ C,
                                                 int M, int N, int K, int tilesN) {
  __shared__ unsigned short lA[2][128 * 64];
  __shared__ unsigned short lB[2][128 * 64];
  int nwg = gridDim.x;
  int cpx = nwg >> 3;                        // all grids are %8==0 (bijective)
  int bid = blockIdx.x;
  int wg = (bid & 7) * cpx + (bid >> 3);
  int tm = wg / tilesN, tn = wg - tm * tilesN;
  int m0 = tm << 7, n0 = tn << 7;
  int tid = threadIdx.x;
  int w = tid >> 6, l = tid & 63;
  int lo = l & 15, hi = l >> 4;
  int srow = tid >> 3, schunk = (tid & 7) * 8;
  int wr = (w >> 1) * 64, wc = (w & 1) * 64;
  int xorv = (l & 7) << 3;
  int nt = K >> 6;
  f32x4 acc[4][4];
#pragma unroll
  for (int i = 0; i < 4; i++)
#pragma unroll
    for (int j = 0; j < 4; j++) acc[i][j] = (f32x4){0.f, 0.f, 0.f, 0.f};

  auto stage = [&](int buf, int t) {
    int k0 = t << 6;
#pragma unroll
    for (int i = 0; i < 4; i++) {
      gl_lds16(A + (size_t)(m0 + i * 32 + srow) * (size_t)K + k0 + schunk,
               &lA[buf][(i * 32 + w * 8) * 64]);
      gl_lds16(Bt + (size_t)(n0 + i * 32 + srow) * (size_t)K + k0 + schunk,
               &lB[buf][(i * 32 + w * 8) * 64]);
    }
  };

  stage(0, 0);
  __syncthreads();
  int cur = 0;
  for (int t = 0; t < nt; t++) {
    if (t + 1 < nt) stage(cur ^ 1, t + 1);   // loads fly during MFMA
#pragma unroll
    for (int kk = 0; kk < 2; kk++) {
      short8 af[4], bfv[4];
#pragma unroll
      for (int i = 0; i < 4; i++) {
        af[i] = *(const short8*)&lA[cur][(wr + i * 16 + lo) * 64 + ((kk * 32 + hi * 8) ^ xorv)];
        bfv[i] = *(const short8*)&lB[cur][(wc + i * 16 + lo) * 64 + ((kk * 32 + hi * 8) ^ xorv)];
      }
#pragma unroll
      for (int i = 0; i < 4; i++)
#pragma unroll
        for (int j = 0; j < 4; j++)
          acc[i][j] = __builtin_amdgcn_mfma_f32_16x16x32_bf16(af[i], bfv[j], acc[i][j], 0, 0, 0);
    }
    __syncthreads();
    cur ^= 1;
  }
  // C/D layout: col = lane&15, row = (lane>>4)*4 + r   [m89]
#pragma unroll
  for (int i = 0; i < 4; i++)
#pragma unroll
    for (int j = 0; j < 4; j++)
#pragma unroll
      for (int r = 0; r < 4; r++)
        C[(size_t)(m0 + wr + i * 16 + hi * 4 + r) * (size_t)N + (n0 + wc + j * 16 + lo)] =
            acc[i][j][r];
}

// ---------------------------------------------------------------------------
// Flash attention v2 (causal, GQA) — barrier-free, no KV staging, fixed-max
// softmax.  512 blocks x 4 waves; each wave owns 32 q-rows and runs fully
// independently (KV served by L1/L2; only a private 4KB P-transpose buffer
// in LDS).  Scores are bounded (|S| <= 128*D^-0.5 = 11.31 after RMSNorm), so
// exp(S) without max-subtraction is safe in fp32: no running max, no rescale,
// no per-tile cross-lane reductions.  Row-sum reduced once at the end.
// ---------------------------------------------------------------------------
__global__ __launch_bounds__(256, 2) void k_attn(const unsigned short* __restrict__ qh,
                                                 const unsigned short* __restrict__ khs,
                                                 const unsigned short* __restrict__ vts,
                                                 unsigned short* __restrict__ ctx) {
  __shared__ unsigned short p_lds[4][32 * 64];   // per-wave private 4KB

  int bid = blockIdx.x;                // 512 blocks
  int b = bid >> 8;
  int h = (bid >> 4) & 15;
  int qt = bid & 15;
  int g = h >> 2;                      // GQA: head h -> group h/4
  int tid = threadIdx.x, w = tid >> 6, l = tid & 63;
  int lo = l & 15, hi = l >> 4, xorv = (l & 7) << 3;
  int q0 = qt * 128 + w * 32;          // this wave's 32 q-rows

  const unsigned short* kg = khs + ((size_t)(b * 4 + g)) * 2048 * 128;
  const unsigned short* vg = vts + ((size_t)(b * 4 + g)) * 128 * 2048;

  // Hoist Q fragments (row=lane&15, k-elems = hi*8..+7 per kd-chunk)
  short8 qf[2][4];
#pragma unroll
  for (int mi = 0; mi < 2; mi++)
#pragma unroll
    for (int kd = 0; kd < 4; kd++)
      qf[mi][kd] = *(const short8*)(qh +
          ((size_t)((b * 16 + h) * 2048 + q0 + mi * 16 + lo)) * 128 + kd * 32 + hi * 8);

  f32x4 accO[2][8];
#pragma unroll
  for (int mi = 0; mi < 2; mi++)
#pragma unroll
    for (int nj = 0; nj < 8; nj++) accO[mi][nj] = (f32x4){0.f, 0.f, 0.f, 0.f};
  float lrun[2][4];
#pragma unroll
  for (int mi = 0; mi < 2; mi++)
#pragma unroll
    for (int r = 0; r < 4; r++) lrun[mi][r] = 0.f;

  int nt = ((q0 + 31) >> 6) + 1;       // KV tiles of 64 this wave needs
  for (int t = 0; t < nt; t++) {
    int s0 = t << 6;

    // ---- K fragments straight from global (L1/L2-served, pre-swizzled) ----
    short8 bf[4][4];
#pragma unroll
    for (int ni = 0; ni < 4; ni++) {
      int row = ni * 16 + lo;
      int sw = (row & 7) << 3;
#pragma unroll
      for (int kd = 0; kd < 4; kd++)
        bf[kd][ni] = *(const short8*)(kg + (size_t)(s0 + row) * 128 + ((kd * 32 + hi * 8) ^ sw));
    }

    // ---- S = Q K^T (q pre-scaled) ----
    f32x4 sc[2][4];
#pragma unroll
    for (int mi = 0; mi < 2; mi++)
#pragma unroll
      for (int ni = 0; ni < 4; ni++) sc[mi][ni] = (f32x4){0.f, 0.f, 0.f, 0.f};
#pragma unroll
    for (int kd = 0; kd < 4; kd++)
#pragma unroll
      for (int ni = 0; ni < 4; ni++) {
        sc[0][ni] = __builtin_amdgcn_mfma_f32_16x16x32_bf16(qf[0][kd], bf[kd][ni], sc[0][ni], 0, 0, 0);
        sc[1][ni] = __builtin_amdgcn_mfma_f32_16x16x32_bf16(qf[1][kd], bf[kd][ni], sc[1][ni], 0, 0, 0);
      }

    // ---- V fragments (issue early so latency hides under exp/P-write) ----
    short8 bv[2][8];
#pragma unroll
    for (int nj = 0; nj < 8; nj++) {
      int d = nj * 16 + lo;
      int swv = (d & 7) << 3;
#pragma unroll
      for (int kt = 0; kt < 2; kt++)
        bv[kt][nj] = *(const short8*)(vg + (size_t)d * 2048 + ((s0 + kt * 32 + hi * 8) ^ swv));
    }

    // ---- causal mask: only the diagonal tile needs it (wave-uniform) ----
    if (t == nt - 1) {
#pragma unroll
      for (int mi = 0; mi < 2; mi++)
#pragma unroll
        for (int ni = 0; ni < 4; ni++)
#pragma unroll
          for (int r = 0; r < 4; r++) {
            int qrow = q0 + mi * 16 + hi * 4 + r;
            int col = s0 + ni * 16 + lo;
            if (col > qrow) sc[mi][ni][r] = -1e30f;
          }
    }

    // ---- P = exp(S) (fixed max = 0), per-lane partial row-sums, P->LDS ----
#pragma unroll
    for (int mi = 0; mi < 2; mi++)
#pragma unroll
      for (int ni = 0; ni < 4; ni++)
#pragma unroll
        for (int r = 0; r < 4; r++) {
          float p = __expf(sc[mi][ni][r]);
          lrun[mi][r] += p;
          int rp = mi * 16 + hi * 4 + r;
          int cp = ni * 16 + lo;
          p_lds[w][rp * 64 + (cp ^ ((rp & 7) << 3))] = f2bf(p);
        }

    // ---- O += P V ----
#pragma unroll
    for (int kt = 0; kt < 2; kt++) {
      short8 pa0 = *(const short8*)&p_lds[w][(lo) * 64 + ((kt * 32 + hi * 8) ^ xorv)];
      short8 pa1 = *(const short8*)&p_lds[w][(16 + lo) * 64 + ((kt * 32 + hi * 8) ^ xorv)];
#pragma unroll
      for (int nj = 0; nj < 8; nj++) {
        accO[0][nj] = __builtin_amdgcn_mfma_f32_16x16x32_bf16(pa0, bv[kt][nj], accO[0][nj], 0, 0, 0);
        accO[1][nj] = __builtin_amdgcn_mfma_f32_16x16x32_bf16(pa1, bv[kt][nj], accO[1][nj], 0, 0, 0);
      }
    }
  }

  // ---- final row-sum reduce across the 16 lo-lanes (once, not per tile) ----
#pragma unroll
  for (int mi = 0; mi < 2; mi++)
#pragma unroll
    for (int r = 0; r < 4; r++) {
      float s = lrun[mi][r];
      s += __shfl_xor(s, 1);
      s += __shfl_xor(s, 2);
      s += __shfl_xor(s, 4);
      s += __shfl_xor(s, 8);
      lrun[mi][r] = s;
    }

  // ---- epilogue: normalize, write ctx (pre-swizzled for GEMM2) ----
#pragma unroll
  for (int mi = 0; mi < 2; mi++)
#pragma unroll
    for (int r = 0; r < 4; r++) {
      float inv = 1.0f / lrun[mi][r];
      int row = b * 2048 + q0 + mi * 16 + hi * 4 + r;
      int sw = (row & 7) << 3;
#pragma unroll
      for (int nj = 0; nj < 8; nj++) {
        int col = h * 128 + nj * 16 + lo;
        ctx[(size_t)row * 2048 + (size_t)(col ^ sw)] = f2bf(accO[mi][nj][r] * inv);
      }
    }
}

// ---------------------------------------------------------------------------
extern "C" void kernel_launch(void* const* d_in, const int* in_sizes, int n_in,
                              void* d_out, int out_size, void* d_ws, size_t ws_size,
                              hipStream_t stream) {
  const float* x    = (const float*)d_in[0];
  // d_in[1] = mask (bool) — causal mask computed analytically, unused
  const float* cosT = (const float*)d_in[2];
  const float* sinT = (const float*)d_in[3];
  const float* Wq   = (const float*)d_in[4];
  const float* Wk   = (const float*)d_in[5];
  const float* Wv   = (const float*)d_in[6];
  const float* Wo   = (const float*)d_in[7];
  const float* qw   = (const float*)d_in[8];
  const float* kw   = (const float*)d_in[9];
  float* out = (float*)d_out;

  char* ws = (char*)d_ws;
  unsigned short* xb    = (unsigned short*)ws; ws += (size_t)4096 * 2048 * 2;
  unsigned short* wqkvT = (unsigned short*)ws; ws += (size_t)3072 * 2048 * 2;
  unsigned short* woT   = (unsigned short*)ws; ws += (size_t)2048 * 2048 * 2;
  float*          qkv   = (float*)ws;          ws += (size_t)4096 * 3072 * 4;
  unsigned short* qh    = (unsigned short*)ws; ws += (size_t)2 * 16 * 2048 * 128 * 2;
  unsigned short* khs   = (unsigned short*)ws; ws += (size_t)2 * 4 * 2048 * 128 * 2;
  unsigned short* vts   = (unsigned short*)ws; ws += (size_t)2 * 4 * 2048 * 128 * 2;
  unsigned short* ctx   = (unsigned short*)ws; ws += (size_t)4096 * 2048 * 2;

  k_cast_x<<<4096, 256, 0, stream>>>(x, xb);
  k_wtrans<<<dim3(32, 32), 256, 0, stream>>>(Wq, wqkvT, 2048, 2048);
  k_wtrans<<<dim3(32, 8),  256, 0, stream>>>(Wk, wqkvT + (size_t)2048 * 2048, 2048, 512);
  k_wtrans<<<dim3(32, 8),  256, 0, stream>>>(Wv, wqkvT + (size_t)2560 * 2048, 2048, 512);
  k_wtrans<<<dim3(32, 32), 256, 0, stream>>>(Wo, woT, 2048, 2048);

  k_gemm<<<768, 256, 0, stream>>>(xb, wqkvT, qkv, 4096, 3072, 2048, 24);
  k_norm_rope<<<20480, 256, 0, stream>>>(qkv, cosT, sinT, qw, kw, qh, khs);
  k_vtrans<<<dim3(32, 2, 8), 256, 0, stream>>>(qkv, vts);
  k_attn<<<512, 256, 0, stream>>>(qh, khs, vts, ctx);
  k_gemm<<<512, 256, 0, stream>>>(ctx, woT, out, 4096, 2048, 2048, 16);
}

// Round 4
// 401.180 us; speedup vs baseline: 1.1085x; 1.1085x over previous
//
#include <hip/hip_runtime.h>
#include <stdint.h>

// Problem constants
// B=2, S=2048, D_IN=2048, H=16, G=4, D=128
// M = B*S = 4096 tokens; QKV N = H*D + 2*G*D = 2048+512+512 = 3072

typedef __attribute__((ext_vector_type(8))) short short8;   // 8 bf16 = 4 VGPRs
typedef __attribute__((ext_vector_type(4))) float f32x4;

__device__ __forceinline__ unsigned short f2bf(float f) {
  unsigned int u = __builtin_bit_cast(unsigned int, f);
  u += 0x7fffu + ((u >> 16) & 1u);   // RNE
  return (unsigned short)(u >> 16);
}

__device__ __forceinline__ void gl_lds16(const void* g, void* l) {
  __builtin_amdgcn_global_load_lds(
      (const __attribute__((address_space(1))) unsigned int*)g,
      (__attribute__((address_space(3))) unsigned int*)l, 16, 0, 0);
}

// ---------------------------------------------------------------------------
// Cast x (f32, row-major [4096][2048]) -> bf16 with per-row XOR swizzle:
// xb[m][k'] where k' = k ^ ((m&7)<<3)   (swizzle on 8-elem chunks)
// ---------------------------------------------------------------------------
__global__ __launch_bounds__(256) void k_cast_x(const float* __restrict__ x,
                                                unsigned short* __restrict__ xb) {
  int t = blockIdx.x * 256 + threadIdx.x;     // 1M threads, 8 elems each
  int m = t >> 8;
  int c = t & 255;                            // chunk of 8 within row
  const float* src = x + ((size_t)m * 2048 + (size_t)c * 8);
  float4 a = *(const float4*)src;
  float4 b = *(const float4*)(src + 4);
  uint4 o;
  o.x = f2bf(a.x) | ((unsigned)f2bf(a.y) << 16);
  o.y = f2bf(a.z) | ((unsigned)f2bf(a.w) << 16);
  o.z = f2bf(b.x) | ((unsigned)f2bf(b.y) << 16);
  o.w = f2bf(b.z) | ((unsigned)f2bf(b.w) << 16);
  *(uint4*)(xb + (size_t)m * 2048 + (size_t)((c ^ (m & 7)) * 8)) = o;
}

// ---------------------------------------------------------------------------
// Weight transpose+cast: W [K][N] f32  ->  WT [N][K] bf16 with row swizzle
// WT[n][k ^ ((n&7)<<3)] = W[k][n].  Tiles 64x64 via padded LDS.
// ---------------------------------------------------------------------------
__global__ __launch_bounds__(256) void k_wtrans(const float* __restrict__ W,
                                                unsigned short* __restrict__ WT,
                                                int K, int N) {
  __shared__ float tile[64][65];
  int k0 = blockIdx.x * 64, n0 = blockIdx.y * 64;
  int c = threadIdx.x & 63, r0 = threadIdx.x >> 6;
#pragma unroll
  for (int i = 0; i < 16; i++) {
    int kl = r0 + i * 4;
    tile[kl][c] = W[(size_t)(k0 + kl) * N + n0 + c];
  }
  __syncthreads();
#pragma unroll
  for (int i = 0; i < 16; i++) {
    int nl = r0 + i * 4;
    int n = n0 + nl;
    int sw = (n & 7) << 3;
    WT[(size_t)n * K + (size_t)((k0 + c) ^ sw)] = f2bf(tile[c][nl]);
  }
}

// ---------------------------------------------------------------------------
// V path: qkv f32 [4096][3072] (cols 2560..3071 = V) -> vts bf16 [(b*G+g)][d][s]
// with s swizzled within rows:  vts[bg][d][s ^ ((d&7)<<3)]
// ---------------------------------------------------------------------------
__global__ __launch_bounds__(256) void k_vtrans(const float* __restrict__ qkv,
                                                unsigned short* __restrict__ vts) {
  __shared__ float tile[64][65];
  int bg = blockIdx.z;
  int s0 = blockIdx.x * 64, d0 = blockIdx.y * 64;
  int b = bg >> 2, g = bg & 3;
  int c = threadIdx.x & 63, r0 = threadIdx.x >> 6;
#pragma unroll
  for (int i = 0; i < 16; i++) {
    int sl = r0 + i * 4;
    tile[sl][c] = qkv[(size_t)(b * 2048 + s0 + sl) * 3072 + 2560 + g * 128 + d0 + c];
  }
  __syncthreads();
#pragma unroll
  for (int i = 0; i < 16; i++) {
    int dl = r0 + i * 4;
    int d = d0 + dl;
    int sw = (d & 7) << 3;
    vts[((size_t)(bg * 128 + d)) * 2048 + (size_t)((s0 + c) ^ sw)] = f2bf(tile[c][dl]);
  }
}

// ---------------------------------------------------------------------------
// RMSNorm + RoPE.  One wave per (token, slot): slots 0..15 = q heads,
// 16..19 = k groups.  Lane holds d=lane and d=lane+64 (rotate-half is local).
// q gets * D^-0.5.  k written pre-swizzled for attention loads.
// ---------------------------------------------------------------------------
__global__ __launch_bounds__(256) void k_norm_rope(const float* __restrict__ qkv,
                                                   const float* __restrict__ cosT,
                                                   const float* __restrict__ sinT,
                                                   const float* __restrict__ qw,
                                                   const float* __restrict__ kw,
                                                   unsigned short* __restrict__ qh,
                                                   unsigned short* __restrict__ khs) {
  int wid = blockIdx.x * 4 + (threadIdx.x >> 6);
  int lane = threadIdx.x & 63;
  int slot = wid % 20;
  int token = wid / 20;              // 0..4095
  int b = token >> 11, s = token & 2047;
  int colbase = (slot < 16) ? slot * 128 : 2048 + (slot - 16) * 128;
  const float* base = qkv + (size_t)token * 3072 + colbase;
  float x1 = base[lane], x2 = base[lane + 64];
  float ss = x1 * x1 + x2 * x2;
#pragma unroll
  for (int o = 1; o < 64; o <<= 1) ss += __shfl_xor(ss, o);
  float rr = rsqrtf(ss * (1.0f / 128.0f) + 1e-6f);
  const float* wv = (slot < 16) ? qw : kw;
  float y1 = x1 * rr * wv[lane];
  float y2 = x2 * rr * wv[lane + 64];
  float c1 = cosT[s * 128 + lane], s1 = sinT[s * 128 + lane];
  float c2 = cosT[s * 128 + lane + 64], s2 = sinT[s * 128 + lane + 64];
  float o1 = y1 * c1 - y2 * s1;      // d < 64:  x*cos - x[d+64]*sin
  float o2 = y2 * c2 + y1 * s2;      // d >= 64: x*cos + x[d-64]*sin
  if (slot < 16) {
    const float sc = 0.08838834764831845f;   // 128^-0.5 folded into q
    unsigned short* dst = qh + ((size_t)((b * 16 + slot) * 2048 + s)) * 128;
    dst[lane] = f2bf(o1 * sc);
    dst[lane + 64] = f2bf(o2 * sc);
  } else {
    int g = slot - 16;
    unsigned short* dst = khs + ((size_t)((b * 4 + g) * 2048 + s)) * 128;
    int sw = (s & 7) << 3;
    dst[lane ^ sw] = f2bf(o1);
    dst[(lane + 64) ^ sw] = f2bf(o2);
  }
}

// ---------------------------------------------------------------------------
// GEMM C[M][N] f32 = A[M][K] * Bt[N][K]   (both bf16, rows XOR-swizzled)
// 128x128 tile, BK=64, 4 waves (64x64 quadrant each), double-buffered LDS,
// global_load_lds width-16, stage-next-before-compute, XCD swizzle.
// ---------------------------------------------------------------------------
__global__ __launch_bounds__(256, 2) void k_gemm(const unsigned short* __restrict__ A,
                                                 const unsigned short* __restrict__ Bt,
                                                 float* __restrict__ C,
                                                 int M, int N, int K, int tilesN) {
  __shared__ unsigned short lA[2][128 * 64];
  __shared__ unsigned short lB[2][128 * 64];
  int nwg = gridDim.x;
  int cpx = nwg >> 3;                        // all grids are %8==0 (bijective)
  int bid = blockIdx.x;
  int wg = (bid & 7) * cpx + (bid >> 3);
  int tm = wg / tilesN, tn = wg - tm * tilesN;
  int m0 = tm << 7, n0 = tn << 7;
  int tid = threadIdx.x;
  int w = tid >> 6, l = tid & 63;
  int lo = l & 15, hi = l >> 4;
  int srow = tid >> 3, schunk = (tid & 7) * 8;
  int wr = (w >> 1) * 64, wc = (w & 1) * 64;
  int xorv = (l & 7) << 3;
  int nt = K >> 6;
  f32x4 acc[4][4];
#pragma unroll
  for (int i = 0; i < 4; i++)
#pragma unroll
    for (int j = 0; j < 4; j++) acc[i][j] = (f32x4){0.f, 0.f, 0.f, 0.f};

  auto stage = [&](int buf, int t) {
    int k0 = t << 6;
#pragma unroll
    for (int i = 0; i < 4; i++) {
      gl_lds16(A + (size_t)(m0 + i * 32 + srow) * (size_t)K + k0 + schunk,
               &lA[buf][(i * 32 + w * 8) * 64]);
      gl_lds16(Bt + (size_t)(n0 + i * 32 + srow) * (size_t)K + k0 + schunk,
               &lB[buf][(i * 32 + w * 8) * 64]);
    }
  };

  stage(0, 0);
  __syncthreads();
  int cur = 0;
  for (int t = 0; t < nt; t++) {
    if (t + 1 < nt) stage(cur ^ 1, t + 1);   // loads fly during MFMA
#pragma unroll
    for (int kk = 0; kk < 2; kk++) {
      short8 af[4], bfv[4];
#pragma unroll
      for (int i = 0; i < 4; i++) {
        af[i] = *(const short8*)&lA[cur][(wr + i * 16 + lo) * 64 + ((kk * 32 + hi * 8) ^ xorv)];
        bfv[i] = *(const short8*)&lB[cur][(wc + i * 16 + lo) * 64 + ((kk * 32 + hi * 8) ^ xorv)];
      }
#pragma unroll
      for (int i = 0; i < 4; i++)
#pragma unroll
        for (int j = 0; j < 4; j++)
          acc[i][j] = __builtin_amdgcn_mfma_f32_16x16x32_bf16(af[i], bfv[j], acc[i][j], 0, 0, 0);
    }
    __syncthreads();
    cur ^= 1;
  }
  // C/D layout: col = lane&15, row = (lane>>4)*4 + r   [m89]
#pragma unroll
  for (int i = 0; i < 4; i++)
#pragma unroll
    for (int j = 0; j < 4; j++)
#pragma unroll
      for (int r = 0; r < 4; r++)
        C[(size_t)(m0 + wr + i * 16 + hi * 4 + r) * (size_t)N + (n0 + wc + j * 16 + lo)] =
            acc[i][j][r];
}

// ---------------------------------------------------------------------------
// Flash attention v3 (causal, GQA) — split-KV + balanced wave-tasks.
// Block = 4 waves = the 4 heads of one group, same (b, qt32, chunk): the
// waves read IDENTICAL K/V lines in near-lockstep -> L1 reuse.  Fixed-max
// softmax makes KV-chunk partials combine by plain addition: heavy q-tiles
// (qt32>=32) are split into 2 chunks writing raw fp32 (O,l) partials to
// per-chunk slots (no atomics); k_combine sums+normalizes.  Light q-tiles
// finalize in-wave and write ctx directly.
// Task map per (b,g), j in [0,96): j<64: qt32 = 63-(j>>1) (heavy, chunk j&1);
// j>=64: qt32 = 95-j (light, full range).  Heavy-first => LPT backfill.
// bid = j*8 + (b*4+g) so bid&7 keys the XCD to one (b,g) KV stream.
// ---------------------------------------------------------------------------
__global__ __launch_bounds__(256, 2) void k_attn(const unsigned short* __restrict__ qh,
                                                 const unsigned short* __restrict__ khs,
                                                 const unsigned short* __restrict__ vts,
                                                 unsigned short* __restrict__ ctx,
                                                 float* __restrict__ Opart,
                                                 float* __restrict__ lsumPart) {
  __shared__ unsigned short p_lds[4][32 * 64];   // per-wave private 4KB

  int bid = blockIdx.x;                // 768 blocks
  int bg = bid & 7, j = bid >> 3;      // j in [0,96)
  int b = bg >> 2, g = bg & 3;
  int tid = threadIdx.x, w = tid >> 6, l = tid & 63;
  int h = g * 4 + w;                   // wave -> head within group
  int lo = l & 15, hi = l >> 4, xorv = (l & 7) << 3;

  int qt32, t0, t1;
  bool partial;
  int slot = j & 1;
  if (j < 64) {                        // heavy: qt32 in [32,63], 2 chunks
    qt32 = 63 - (j >> 1);
    int nt = (qt32 >> 1) + 1;          // 17..32
    int half = nt >> 1;
    t0 = slot ? half : 0;
    t1 = slot ? nt : half;
    partial = true;
  } else {                             // light: qt32 in [0,31], full range
    qt32 = 95 - j;
    t0 = 0;
    t1 = (qt32 >> 1) + 1;              // 1..16
    partial = false;
  }
  int q0 = qt32 * 32;                  // this wave's 32 q-rows
  int ntm1 = qt32 >> 1;                // last (diagonal) tile index

  const unsigned short* kg = khs + ((size_t)(b * 4 + g)) * 2048 * 128;
  const unsigned short* vg = vts + ((size_t)(b * 4 + g)) * 128 * 2048;

  // Hoist Q fragments (row=lane&15, k-elems = hi*8..+7 per kd-chunk)
  short8 qf[2][4];
#pragma unroll
  for (int mi = 0; mi < 2; mi++)
#pragma unroll
    for (int kd = 0; kd < 4; kd++)
      qf[mi][kd] = *(const short8*)(qh +
          ((size_t)((b * 16 + h) * 2048 + q0 + mi * 16 + lo)) * 128 + kd * 32 + hi * 8);

  f32x4 accO[2][8];
#pragma unroll
  for (int mi = 0; mi < 2; mi++)
#pragma unroll
    for (int nj = 0; nj < 8; nj++) accO[mi][nj] = (f32x4){0.f, 0.f, 0.f, 0.f};
  float lrun[2][4];
#pragma unroll
  for (int mi = 0; mi < 2; mi++)
#pragma unroll
    for (int r = 0; r < 4; r++) lrun[mi][r] = 0.f;

  for (int t = t0; t < t1; t++) {
    int s0 = t << 6;

    // ---- K fragments from global (L1-shared across the 4 waves) ----
    short8 bf[4][4];
#pragma unroll
    for (int ni = 0; ni < 4; ni++) {
      int row = ni * 16 + lo;
      int sw = (row & 7) << 3;
#pragma unroll
      for (int kd = 0; kd < 4; kd++)
        bf[kd][ni] = *(const short8*)(kg + (size_t)(s0 + row) * 128 + ((kd * 32 + hi * 8) ^ sw));
    }

    // ---- S = Q K^T (q pre-scaled) ----
    f32x4 sc[2][4];
#pragma unroll
    for (int mi = 0; mi < 2; mi++)
#pragma unroll
      for (int ni = 0; ni < 4; ni++) sc[mi][ni] = (f32x4){0.f, 0.f, 0.f, 0.f};
#pragma unroll
    for (int kd = 0; kd < 4; kd++)
#pragma unroll
      for (int ni = 0; ni < 4; ni++) {
        sc[0][ni] = __builtin_amdgcn_mfma_f32_16x16x32_bf16(qf[0][kd], bf[kd][ni], sc[0][ni], 0, 0, 0);
        sc[1][ni] = __builtin_amdgcn_mfma_f32_16x16x32_bf16(qf[1][kd], bf[kd][ni], sc[1][ni], 0, 0, 0);
      }

    // ---- V fragments (issue early so latency hides under exp/P-write) ----
    short8 bv[2][8];
#pragma unroll
    for (int nj = 0; nj < 8; nj++) {
      int d = nj * 16 + lo;
      int swv = (d & 7) << 3;
#pragma unroll
      for (int kt = 0; kt < 2; kt++)
        bv[kt][nj] = *(const short8*)(vg + (size_t)d * 2048 + ((s0 + kt * 32 + hi * 8) ^ swv));
    }

    // ---- causal mask: only the diagonal tile needs it ----
    if (t == ntm1) {
#pragma unroll
      for (int mi = 0; mi < 2; mi++)
#pragma unroll
        for (int ni = 0; ni < 4; ni++)
#pragma unroll
          for (int r = 0; r < 4; r++) {
            int qrow = q0 + mi * 16 + hi * 4 + r;
            int col = s0 + ni * 16 + lo;
            if (col > qrow) sc[mi][ni][r] = -1e30f;
          }
    }

    // ---- P = exp(S) (fixed max = 0), per-lane partial row-sums, P->LDS ----
#pragma unroll
    for (int mi = 0; mi < 2; mi++)
#pragma unroll
      for (int ni = 0; ni < 4; ni++)
#pragma unroll
        for (int r = 0; r < 4; r++) {
          float p = __expf(sc[mi][ni][r]);
          lrun[mi][r] += p;
          int rp = mi * 16 + hi * 4 + r;
          int cp = ni * 16 + lo;
          p_lds[w][rp * 64 + (cp ^ ((rp & 7) << 3))] = f2bf(p);
        }

    // ---- O += P V ----
#pragma unroll
    for (int kt = 0; kt < 2; kt++) {
      short8 pa0 = *(const short8*)&p_lds[w][(lo) * 64 + ((kt * 32 + hi * 8) ^ xorv)];
      short8 pa1 = *(const short8*)&p_lds[w][(16 + lo) * 64 + ((kt * 32 + hi * 8) ^ xorv)];
#pragma unroll
      for (int nj = 0; nj < 8; nj++) {
        accO[0][nj] = __builtin_amdgcn_mfma_f32_16x16x32_bf16(pa0, bv[kt][nj], accO[0][nj], 0, 0, 0);
        accO[1][nj] = __builtin_amdgcn_mfma_f32_16x16x32_bf16(pa1, bv[kt][nj], accO[1][nj], 0, 0, 0);
      }
    }
  }

  // ---- final row-sum reduce across the 16 lo-lanes ----
#pragma unroll
  for (int mi = 0; mi < 2; mi++)
#pragma unroll
    for (int r = 0; r < 4; r++) {
      float s = lrun[mi][r];
      s += __shfl_xor(s, 1);
      s += __shfl_xor(s, 2);
      s += __shfl_xor(s, 4);
      s += __shfl_xor(s, 8);
      lrun[mi][r] = s;
    }

  if (!partial) {
    // ---- complete row: normalize, write ctx (pre-swizzled for GEMM2) ----
#pragma unroll
    for (int mi = 0; mi < 2; mi++)
#pragma unroll
      for (int r = 0; r < 4; r++) {
        float inv = 1.0f / lrun[mi][r];
        int row = b * 2048 + q0 + mi * 16 + hi * 4 + r;
        int sw = (row & 7) << 3;
#pragma unroll
        for (int nj = 0; nj < 8; nj++) {
          int col = h * 128 + nj * 16 + lo;
          ctx[(size_t)row * 2048 + (size_t)(col ^ sw)] = f2bf(accO[mi][nj][r] * inv);
        }
      }
  } else {
    // ---- KV-chunk partial: raw fp32 (O, l) to per-chunk slot ----
    float* Ob = Opart + ((((size_t)slot * 2 + b) * 16 + h) * 1024) * 128;
#pragma unroll
    for (int mi = 0; mi < 2; mi++)
#pragma unroll
      for (int r = 0; r < 4; r++) {
        int srel = q0 - 1024 + mi * 16 + hi * 4 + r;   // rows 1024..2047
#pragma unroll
        for (int nj = 0; nj < 8; nj++)
          Ob[(size_t)srel * 128 + nj * 16 + lo] = accO[mi][nj][r];
        if (lo == 0)
          lsumPart[(((size_t)slot * 2 + b) * 16 + h) * 1024 + srel] = lrun[mi][r];
      }
  }
}

// ---------------------------------------------------------------------------
// Combine the two KV-chunk partials for rows 1024..2047: O=(O0+O1)/(l0+l1),
// cast to bf16, write ctx pre-swizzled.  Thread = 4 consecutive d.
// ---------------------------------------------------------------------------
__global__ __launch_bounds__(256) void k_combine(const float* __restrict__ Opart,
                                                 const float* __restrict__ lsumPart,
                                                 unsigned short* __restrict__ ctx) {
  const size_t SLOT = (size_t)2 * 16 * 1024 * 128;
  int t = blockIdx.x * 256 + threadIdx.x;    // 1,048,576 threads
  int d4 = t & 31;
  int srel = (t >> 5) & 1023;
  int h = (t >> 15) & 15;
  int b = (t >> 19) & 1;
  size_t base = (((size_t)b * 16 + h) * 1024 + srel) * 128 + d4 * 4;
  float4 o0 = *(const float4*)(Opart + base);
  float4 o1 = *(const float4*)(Opart + SLOT + base);
  size_t lidx = ((size_t)b * 16 + h) * 1024 + srel;
  float inv = 1.0f / (lsumPart[lidx] + lsumPart[(size_t)2 * 16 * 1024 + lidx]);
  int s = 1024 + srel;
  int row = b * 2048 + s;
  int col = h * 128 + d4 * 4;
  int sw = (s & 7) << 3;
  ushort4 o;
  o.x = f2bf((o0.x + o1.x) * inv);
  o.y = f2bf((o0.y + o1.y) * inv);
  o.z = f2bf((o0.z + o1.z) * inv);
  o.w = f2bf((o0.w + o1.w) * inv);
  *(ushort4*)(ctx + (size_t)row * 2048 + (size_t)(col ^ sw)) = o;
}

// ---------------------------------------------------------------------------
extern "C" void kernel_launch(void* const* d_in, const int* in_sizes, int n_in,
                              void* d_out, int out_size, void* d_ws, size_t ws_size,
                              hipStream_t stream) {
  const float* x    = (const float*)d_in[0];
  // d_in[1] = mask (bool) — causal mask computed analytically, unused
  const float* cosT = (const float*)d_in[2];
  const float* sinT = (const float*)d_in[3];
  const float* Wq   = (const float*)d_in[4];
  const float* Wk   = (const float*)d_in[5];
  const float* Wv   = (const float*)d_in[6];
  const float* Wo   = (const float*)d_in[7];
  const float* qw   = (const float*)d_in[8];
  const float* kw   = (const float*)d_in[9];
  float* out = (float*)d_out;

  char* ws = (char*)d_ws;
  unsigned short* xb    = (unsigned short*)ws; ws += (size_t)4096 * 2048 * 2;
  unsigned short* wqkvT = (unsigned short*)ws; ws += (size_t)3072 * 2048 * 2;
  unsigned short* woT   = (unsigned short*)ws; ws += (size_t)2048 * 2048 * 2;
  float*          qkv   = (float*)ws;          ws += (size_t)4096 * 3072 * 4;
  unsigned short* qh    = (unsigned short*)ws; ws += (size_t)2 * 16 * 2048 * 128 * 2;
  unsigned short* khs   = (unsigned short*)ws; ws += (size_t)2 * 4 * 2048 * 128 * 2;
  unsigned short* vts   = (unsigned short*)ws; ws += (size_t)2 * 4 * 2048 * 128 * 2;
  unsigned short* ctx   = (unsigned short*)ws; ws += (size_t)4096 * 2048 * 2;
  float*       lsumPart = (float*)ws;          ws += (size_t)2 * 2 * 16 * 1024 * 4;
  // Opart (2 slots x 2 x 16 x 1024 x 128 f32 = 33.5 MB) aliases qkv (48 MB):
  // qkv is dead after k_norm_rope/k_vtrans, both of which precede k_attn.
  float* Opart = qkv;

  k_cast_x<<<4096, 256, 0, stream>>>(x, xb);
  k_wtrans<<<dim3(32, 32), 256, 0, stream>>>(Wq, wqkvT, 2048, 2048);
  k_wtrans<<<dim3(32, 8),  256, 0, stream>>>(Wk, wqkvT + (size_t)2048 * 2048, 2048, 512);
  k_wtrans<<<dim3(32, 8),  256, 0, stream>>>(Wv, wqkvT + (size_t)2560 * 2048, 2048, 512);
  k_wtrans<<<dim3(32, 32), 256, 0, stream>>>(Wo, woT, 2048, 2048);

  k_gemm<<<768, 256, 0, stream>>>(xb, wqkvT, qkv, 4096, 3072, 2048, 24);
  k_norm_rope<<<20480, 256, 0, stream>>>(qkv, cosT, sinT, qw, kw, qh, khs);
  k_vtrans<<<dim3(32, 2, 8), 256, 0, stream>>>(qkv, vts);
  k_attn<<<768, 256, 0, stream>>>(qh, khs, vts, ctx, Opart, lsumPart);
  k_combine<<<4096, 256, 0, stream>>>(Opart, lsumPart, ctx);
  k_gemm<<<512, 256, 0, stream>>>(ctx, woT, out, 4096, 2048, 2048, 16);
}